// Round 1
// baseline (560.892 us; speedup 1.0000x reference)
//
#include <hip/hip_runtime.h>

#define N_S   65536
#define DXF   1024
#define DD    256
#define NM1   65535.0f
#define EPSR  0.001f

typedef __attribute__((ext_vector_type(4))) float          f32x4;
typedef __attribute__((ext_vector_type(8))) short          bf16x8;
typedef __attribute__((ext_vector_type(4))) unsigned short ushort4_t;
typedef __attribute__((ext_vector_type(8))) unsigned short ushort8_t;

__device__ __forceinline__ unsigned short f2bf(float f){
  unsigned u = __float_as_uint(f);
  u += 0x7fffu + ((u >> 16) & 1u);   // RNE
  return (unsigned short)(u >> 16);
}
__device__ __forceinline__ float bf2f(unsigned short h){
  return __uint_as_float(((unsigned)h) << 16);
}
__device__ __forceinline__ f32x4 mfma16(bf16x8 a, bf16x8 b, f32x4 c){
  return __builtin_amdgcn_mfma_f32_16x16x32_bf16(a, b, c, 0, 0, 0);
}

// ---------------- scalars: STG regularizers + zero the column-sum buffers --
__global__ void k_scalars(const float* __restrict__ mux, const float* __restrict__ muy,
                          float* __restrict__ sx, float* __restrict__ sy,
                          float* __restrict__ scal){
  __shared__ float red[512];
  int v = blockIdx.x;
  const float* mu = v ? muy : mux;
  int t = threadIdx.x;
  float a = 0.5f * (1.f + erff(mu[t]       * 1.41421356237f));
  float b = 0.5f * (1.f + erff(mu[t + 512] * 1.41421356237f));
  red[t] = a + b;
  __syncthreads();
  for (int s = 256; s > 0; s >>= 1){
    if (t < s) red[t] += red[t + s];
    __syncthreads();
  }
  if (t == 0) scal[2 + v] = 0.1f * red[0] / 1024.f;
  if (t < 256) (v ? sy : sx)[t] = 0.f;
}

// ---------------- build W'^T = (diag(gate)*W)^T in bf16, [256][1024] -------
__global__ void k_prep(const float* __restrict__ Wx, const float* __restrict__ Wy,
                       const float* __restrict__ mux, const float* __restrict__ muy,
                       unsigned short* __restrict__ WTx, unsigned short* __restrict__ WTy){
  int v = blockIdx.y;
  const float* W  = v ? Wy  : Wx;
  const float* mu = v ? muy : mux;
  unsigned short* WT = v ? WTy : WTx;
  int j = threadIdx.x;
  #pragma unroll
  for (int r = 0; r < 4; ++r){
    int k = blockIdx.x * 4 + r;
    float g = fminf(fmaxf(mu[k] + 0.5f, 0.f), 1.f);
    WT[(size_t)j * DXF + k] = f2bf(g * W[(size_t)k * DD + j]);
  }
}

// ---------------- big GEMM: Xh = X @ W'  (65536x1024 @ 1024x256) -> bf16 ---
// block tile 128x256, 8 waves (2x4), wave tile 64x64, K-step 32
__global__ __launch_bounds__(512) void k_gemm1(
    const float* __restrict__ X, const float* __restrict__ Y,
    const unsigned short* __restrict__ WTx, const unsigned short* __restrict__ WTy,
    unsigned short* __restrict__ Xhb, unsigned short* __restrict__ Yhb){
  const float* A = blockIdx.z ? Y : X;
  const unsigned short* WT = blockIdx.z ? WTy : WTx;
  unsigned short* Out = blockIdx.z ? Yhb : Xhb;

  __shared__ unsigned short As[128][40];   // [row][k] bf16
  __shared__ unsigned short Bs[256][40];   // [col][k] bf16

  int tid = threadIdx.x;
  int lane = tid & 63, wid = tid >> 6;
  int wr = wid >> 2, wc = wid & 3;
  int row0 = blockIdx.x * 128;

  f32x4 acc[4][4] = {};

  float4    ar[2];
  ushort8_t br[2];
  int arow[2], akq[2], bcol[2], bkq[2];
  #pragma unroll
  for (int r = 0; r < 2; ++r){
    int ia = r * 512 + tid;
    arow[r] = ia >> 3; akq[r] = ia & 7;    // 128 rows x 8 float4
    bcol[r] = ia >> 2; bkq[r] = ia & 3;    // 256 cols x 4 short8
  }

  auto loadT = [&](int kt){
    #pragma unroll
    for (int r = 0; r < 2; ++r){
      ar[r] = *(const float4*)(A + (size_t)(row0 + arow[r]) * DXF + kt * 32 + akq[r] * 4);
      br[r] = *(const ushort8_t*)(WT + (size_t)bcol[r] * DXF + kt * 32 + bkq[r] * 8);
    }
  };

  loadT(0);
  for (int kt = 0; kt < 32; ++kt){
    __syncthreads();
    #pragma unroll
    for (int r = 0; r < 2; ++r){
      ushort4_t w = { f2bf(ar[r].x), f2bf(ar[r].y), f2bf(ar[r].z), f2bf(ar[r].w) };
      *(ushort4_t*)&As[arow[r]][akq[r] * 4] = w;
      *(ushort8_t*)&Bs[bcol[r]][bkq[r] * 8] = br[r];
    }
    __syncthreads();
    if (kt + 1 < 32) loadT(kt + 1);
    bf16x8 af[4], bfv[4];
    #pragma unroll
    for (int mi = 0; mi < 4; ++mi)
      af[mi] = *(const bf16x8*)&As[wr * 64 + mi * 16 + (lane & 15)][(lane >> 4) * 8];
    #pragma unroll
    for (int ni = 0; ni < 4; ++ni)
      bfv[ni] = *(const bf16x8*)&Bs[wc * 64 + ni * 16 + (lane & 15)][(lane >> 4) * 8];
    #pragma unroll
    for (int mi = 0; mi < 4; ++mi)
      #pragma unroll
      for (int ni = 0; ni < 4; ++ni)
        acc[mi][ni] = mfma16(af[mi], bfv[ni], acc[mi][ni]);
  }
  #pragma unroll
  for (int mi = 0; mi < 4; ++mi)
    #pragma unroll
    for (int ni = 0; ni < 4; ++ni)
      #pragma unroll
      for (int rr = 0; rr < 4; ++rr){
        int row = row0 + wr * 64 + mi * 16 + (lane >> 4) * 4 + rr;
        int col = wc * 64 + ni * 16 + (lane & 15);
        Out[(size_t)row * DD + col] = f2bf(acc[mi][ni][rr]);
      }
}

// ---------------- Gram kernel: split-K partials of Xh^T Xh / Yh^T Yh / Yh^T Xh
// block: 512 thr (8 waves, 4x2), output 256x256, K-chunk = 65536/P
__global__ __launch_bounds__(512) void k_gram(
    const unsigned short* __restrict__ Xhb, const unsigned short* __restrict__ Yhb,
    float* __restrict__ part, float* __restrict__ sx, float* __restrict__ sy, int P){
  int type = blockIdx.z;                   // 0:xx 1:yy 2:yx
  int p = blockIdx.x;
  int chunk = N_S / P;
  int r0 = p * chunk;
  const unsigned short* Asrc = (type == 0) ? Xhb : Yhb;
  const unsigned short* Bsrc = (type == 1) ? Yhb : Xhb;
  bool dualB = (type == 2);

  __shared__ unsigned short At[256][40];   // [col][k] bf16 (transposed tile)
  __shared__ unsigned short Bt[256][40];

  int tid = threadIdx.x;
  int lane = tid & 63, wid = tid >> 6;
  int wr = wid >> 1, wc = wid & 1;

  f32x4 acc[4][8] = {};
  float cs0 = 0.f, cs1 = 0.f;

  int cp  = tid & 127;                     // column pair (cols cp*2, cp*2+1)
  int kb0 = tid >> 7;                      // 0..3 ; rep adds +4

  unsigned ua[2][4], ub[2][4];

  auto loadT = [&](int ks){
    int base = r0 + ks * 32;
    #pragma unroll
    for (int r = 0; r < 2; ++r){
      int kb = kb0 + r * 4;
      #pragma unroll
      for (int kr = 0; kr < 4; ++kr){
        ua[r][kr] = *(const unsigned*)(Asrc + (size_t)(base + kb * 4 + kr) * DD + cp * 2);
        if (dualB)
          ub[r][kr] = *(const unsigned*)(Bsrc + (size_t)(base + kb * 4 + kr) * DD + cp * 2);
      }
    }
  };
  auto storeT = [&](){
    #pragma unroll
    for (int r = 0; r < 2; ++r){
      int kb = kb0 + r * 4;
      ushort4_t lo = { (unsigned short)ua[r][0], (unsigned short)ua[r][1],
                       (unsigned short)ua[r][2], (unsigned short)ua[r][3] };
      ushort4_t hi = { (unsigned short)(ua[r][0] >> 16), (unsigned short)(ua[r][1] >> 16),
                       (unsigned short)(ua[r][2] >> 16), (unsigned short)(ua[r][3] >> 16) };
      *(ushort4_t*)&At[cp * 2][kb * 4]     = lo;
      *(ushort4_t*)&At[cp * 2 + 1][kb * 4] = hi;
      if (type < 2){
        #pragma unroll
        for (int kr = 0; kr < 4; ++kr){
          cs0 += bf2f((unsigned short)ua[r][kr]);
          cs1 += bf2f((unsigned short)(ua[r][kr] >> 16));
        }
      }
      if (dualB){
        ushort4_t lob = { (unsigned short)ub[r][0], (unsigned short)ub[r][1],
                          (unsigned short)ub[r][2], (unsigned short)ub[r][3] };
        ushort4_t hib = { (unsigned short)(ub[r][0] >> 16), (unsigned short)(ub[r][1] >> 16),
                          (unsigned short)(ub[r][2] >> 16), (unsigned short)(ub[r][3] >> 16) };
        *(ushort4_t*)&Bt[cp * 2][kb * 4]     = lob;
        *(ushort4_t*)&Bt[cp * 2 + 1][kb * 4] = hib;
      }
    }
  };

  unsigned short (*Btp)[40] = dualB ? Bt : At;

  int KS = chunk / 32;
  loadT(0);
  for (int ks = 0; ks < KS; ++ks){
    __syncthreads();
    storeT();
    __syncthreads();
    if (ks + 1 < KS) loadT(ks + 1);
    bf16x8 af[4], bfv[8];
    #pragma unroll
    for (int mi = 0; mi < 4; ++mi)
      af[mi] = *(const bf16x8*)&At[wr * 64 + mi * 16 + (lane & 15)][(lane >> 4) * 8];
    #pragma unroll
    for (int ni = 0; ni < 8; ++ni)
      bfv[ni] = *(const bf16x8*)&Btp[wc * 128 + ni * 16 + (lane & 15)][(lane >> 4) * 8];
    #pragma unroll
    for (int mi = 0; mi < 4; ++mi)
      #pragma unroll
      for (int ni = 0; ni < 8; ++ni)
        acc[mi][ni] = mfma16(af[mi], bfv[ni], acc[mi][ni]);
  }

  float* dst = part + ((size_t)p * 3 + type) * 65536;
  #pragma unroll
  for (int mi = 0; mi < 4; ++mi)
    #pragma unroll
    for (int ni = 0; ni < 8; ++ni)
      #pragma unroll
      for (int rr = 0; rr < 4; ++rr){
        int grow = wr * 64 + mi * 16 + (lane >> 4) * 4 + rr;
        int gcol = wc * 128 + ni * 16 + (lane & 15);
        dst[(size_t)grow * 256 + gcol] = acc[mi][ni][rr];
      }

  if (type < 2){
    __syncthreads();
    float* red = (float*)&At[0][0];        // 4*256 floats
    red[kb0 * 256 + cp * 2]     = cs0;
    red[kb0 * 256 + cp * 2 + 1] = cs1;
    __syncthreads();
    if (tid < 256){
      float s = red[tid] + red[256 + tid] + red[512 + tid] + red[768 + tid];
      atomicAdd((type == 0 ? sx : sy) + tid, s);
    }
  }
}

// ---------------- reduce partials -> A = Cyy+2eI, B = Cxx+eI, Cyx ----------
__global__ void k_reduce(const float* __restrict__ part, const float* __restrict__ sx,
                         const float* __restrict__ sy, float* __restrict__ Am,
                         float* __restrict__ Bm, float* __restrict__ Cyx, int P){
  int i = blockIdx.x, j = threadIdx.x;
  size_t idx = (size_t)i * 256 + j;
  float gxx = 0.f, gyy = 0.f, gyx = 0.f;
  for (int p = 0; p < P; ++p){
    const float* b = part + (size_t)p * 3 * 65536;
    gxx += b[idx];
    gyy += b[65536 + idx];
    gyx += b[131072 + idx];
  }
  float invn1 = 1.f / NM1;
  float invn  = 1.f / (float)N_S;
  float sxi = sx[i], sxj = sx[j], syi = sy[i], syj = sy[j];
  float diag = (i == j) ? 1.f : 0.f;
  Am[idx]  = (gyy - syi * syj * invn) * invn1 + diag * (2.f * EPSR);
  Bm[idx]  = (gxx - sxi * sxj * invn) * invn1 + diag * EPSR;
  Cyx[idx] = (gyx - syi * sxj * invn) * invn1;
}

// ---------------- alpha = 1/||A||_inf, 1/||B||_inf -------------------------
__global__ void k_norm(const float* __restrict__ Am, const float* __restrict__ Bm,
                       float* __restrict__ scal){
  __shared__ float red[256];
  int i = threadIdx.x;
  float ra = 0.f, rb = 0.f;
  for (int j = 0; j < 256; ++j){
    ra += fabsf(Am[(size_t)i * 256 + j]);
    rb += fabsf(Bm[(size_t)i * 256 + j]);
  }
  red[i] = ra; __syncthreads();
  for (int s = 128; s > 0; s >>= 1){ if (i < s) red[i] = fmaxf(red[i], red[i + s]); __syncthreads(); }
  if (i == 0) scal[0] = 1.f / red[0];
  __syncthreads();
  red[i] = rb; __syncthreads();
  for (int s = 128; s > 0; s >>= 1){ if (i < s) red[i] = fmaxf(red[i], red[i + s]); __syncthreads(); }
  if (i == 0) scal[1] = 1.f / red[0];
}

__global__ void k_init(float* __restrict__ Xa, float* __restrict__ Xb,
                       const float* __restrict__ scal){
  int v = blockIdx.y, i = blockIdx.x, j = threadIdx.x;
  float* Xc = v ? Xb : Xa;
  Xc[(size_t)i * 256 + j] = (i == j) ? scal[v] : 0.f;
}

// ---------------- Newton-Schulz helpers (256^3 fp32 GEMMs) -----------------
__global__ void k_nsmm(const float* __restrict__ Am, const float* __restrict__ Bm,
                       const float* __restrict__ Xa, const float* __restrict__ Xb,
                       float* __restrict__ Ta, float* __restrict__ Tb){
  const float* M  = blockIdx.z ? Bm : Am;
  const float* Xc = blockIdx.z ? Xb : Xa;
  float* T        = blockIdx.z ? Tb : Ta;
  int tx = threadIdx.x & 15, ty = threadIdx.x >> 4;
  int row = blockIdx.y * 16 + ty, col = blockIdx.x * 16 + tx;
  float s = 0.f;
  #pragma unroll 8
  for (int k = 0; k < 256; ++k) s += M[(size_t)row * 256 + k] * Xc[(size_t)k * 256 + col];
  T[(size_t)row * 256 + col] = s;
}
__global__ void k_nsupd(const float* __restrict__ Xa, const float* __restrict__ Xb,
                        const float* __restrict__ Ta, const float* __restrict__ Tb,
                        float* __restrict__ Na, float* __restrict__ Nb){
  const float* Xc = blockIdx.z ? Xb : Xa;
  const float* T  = blockIdx.z ? Tb : Ta;
  float* Nn       = blockIdx.z ? Nb : Na;
  int tx = threadIdx.x & 15, ty = threadIdx.x >> 4;
  int row = blockIdx.y * 16 + ty, col = blockIdx.x * 16 + tx;
  float s = 0.f;
  #pragma unroll 8
  for (int k = 0; k < 256; ++k) s += Xc[(size_t)row * 256 + k] * T[(size_t)k * 256 + col];
  Nn[(size_t)row * 256 + col] = 2.f * Xc[(size_t)row * 256 + col] - s;
}

// ---------------- U = A^-1 Cyx ; V = B^-1 Cyx^T ----------------------------
__global__ void k_uv(const float* __restrict__ Xa, const float* __restrict__ Xb,
                     const float* __restrict__ Cyx, float* __restrict__ U,
                     float* __restrict__ V){
  int z = blockIdx.z;
  int tx = threadIdx.x & 15, ty = threadIdx.x >> 4;
  int row = blockIdx.y * 16 + ty, col = blockIdx.x * 16 + tx;
  float s = 0.f;
  if (z == 0){
    #pragma unroll 8
    for (int k = 0; k < 256; ++k) s += Xa[(size_t)row * 256 + k] * Cyx[(size_t)k * 256 + col];
    U[(size_t)row * 256 + col] = s;
  } else {
    #pragma unroll 8
    for (int k = 0; k < 256; ++k) s += Xb[(size_t)row * 256 + k] * Cyx[(size_t)col * 256 + k];
    V[(size_t)row * 256 + col] = s;
  }
}

// ---------------- final: loss = -trace(U V)/256 + reg_x + reg_y ------------
__global__ void k_final(const float* __restrict__ U, const float* __restrict__ V,
                        const float* __restrict__ scal, float* __restrict__ out){
  __shared__ float red[256];
  int i = threadIdx.x;
  float s = 0.f;
  for (int j = 0; j < 256; ++j) s += U[(size_t)i * 256 + j] * V[(size_t)j * 256 + i];
  red[i] = s; __syncthreads();
  for (int st = 128; st > 0; st >>= 1){ if (i < st) red[i] += red[i + st]; __syncthreads(); }
  if (i == 0) out[0] = -red[0] / 256.f + scal[2] + scal[3];
}

extern "C" void kernel_launch(void* const* d_in, const int* in_sizes, int n_in,
                              void* d_out, int out_size, void* d_ws, size_t ws_size,
                              hipStream_t stream){
  (void)in_sizes; (void)n_in; (void)out_size;
  const float* X   = (const float*)d_in[0];
  const float* Y   = (const float*)d_in[1];
  const float* mux = (const float*)d_in[2];
  const float* muy = (const float*)d_in[3];
  const float* Wx  = (const float*)d_in[4];
  const float* Wy  = (const float*)d_in[6];
  float* out = (float*)d_out;
  char* ws = (char*)d_ws;

  const size_t MB = 1ull << 20;
  const size_t KB256 = 256ull * 1024;
  size_t oXHB = 0;
  size_t oYHB = 32 * MB;
  size_t oWTX = 64 * MB;
  size_t oWTY = oWTX + 512 * 1024;
  size_t oSX  = oWTY + 512 * 1024;
  size_t oSY  = oSX + 4096;
  size_t oSC  = oSY + 4096;
  size_t oA   = oSC + 4096;
  size_t oB   = oA + KB256;
  size_t oC   = oB + KB256;
  size_t oXA0 = oC + KB256;
  size_t oXB0 = oXA0 + KB256;
  size_t oXA1 = oXB0 + KB256;
  size_t oXB1 = oXA1 + KB256;
  size_t oTA  = oXB1 + KB256;
  size_t oTB  = oTA + KB256;
  size_t oU   = oTB + KB256;
  size_t oV   = oU + KB256;
  size_t oPart = oV + KB256;

  size_t per = 3ull * 65536 * 4;
  int P = 64;
  while (P > 1 && oPart + (size_t)P * per > ws_size) P >>= 1;

  unsigned short* Xhb = (unsigned short*)(ws + oXHB);
  unsigned short* Yhb = (unsigned short*)(ws + oYHB);
  unsigned short* WTx = (unsigned short*)(ws + oWTX);
  unsigned short* WTy = (unsigned short*)(ws + oWTY);
  float* sx   = (float*)(ws + oSX);
  float* sy   = (float*)(ws + oSY);
  float* scal = (float*)(ws + oSC);
  float* Am   = (float*)(ws + oA);
  float* Bm   = (float*)(ws + oB);
  float* Cyx  = (float*)(ws + oC);
  float* XA0  = (float*)(ws + oXA0);
  float* XB0  = (float*)(ws + oXB0);
  float* XA1  = (float*)(ws + oXA1);
  float* XB1  = (float*)(ws + oXB1);
  float* Ta   = (float*)(ws + oTA);
  float* Tb   = (float*)(ws + oTB);
  float* U    = (float*)(ws + oU);
  float* V    = (float*)(ws + oV);
  float* part = (float*)(ws + oPart);

  k_scalars<<<2, 512, 0, stream>>>(mux, muy, sx, sy, scal);
  k_prep<<<dim3(256, 2), 256, 0, stream>>>(Wx, Wy, mux, muy, WTx, WTy);
  k_gemm1<<<dim3(512, 1, 2), 512, 0, stream>>>(X, Y, WTx, WTy, Xhb, Yhb);
  k_gram<<<dim3(P, 1, 3), 512, 0, stream>>>(Xhb, Yhb, part, sx, sy, P);
  k_reduce<<<256, 256, 0, stream>>>(part, sx, sy, Am, Bm, Cyx, P);
  k_norm<<<1, 256, 0, stream>>>(Am, Bm, scal);
  k_init<<<dim3(256, 2), 256, 0, stream>>>(XA0, XB0, scal);

  float *xa = XA0, *xb = XB0, *na = XA1, *nb = XB1;
  for (int it = 0; it < 11; ++it){
    k_nsmm<<<dim3(16, 16, 2), 256, 0, stream>>>(Am, Bm, xa, xb, Ta, Tb);
    k_nsupd<<<dim3(16, 16, 2), 256, 0, stream>>>(xa, xb, Ta, Tb, na, nb);
    float* t;
    t = xa; xa = na; na = t;
    t = xb; xb = nb; nb = t;
  }

  k_uv<<<dim3(16, 16, 2), 256, 0, stream>>>(xa, xb, Cyx, U, V);
  k_final<<<1, 256, 0, stream>>>(U, V, scal, out);
}

// Round 2
// 519.237 us; speedup vs baseline: 1.0802x; 1.0802x over previous
//
#include <hip/hip_runtime.h>
#include <hip/hip_cooperative_groups.h>

namespace cg = cooperative_groups;

#define N_S   65536
#define DXF   1024
#define DD    256
#define NM1   65535.0f
#define EPSR  0.001f

typedef __attribute__((ext_vector_type(4)))  float          f32x4;
typedef __attribute__((ext_vector_type(16))) float          f32x16;
typedef __attribute__((ext_vector_type(8)))  short          bf16x8;
typedef __attribute__((ext_vector_type(4)))  unsigned short ushort4_t;
typedef __attribute__((ext_vector_type(8)))  unsigned short ushort8_t;

__device__ __forceinline__ unsigned short f2bf(float f){
  unsigned u = __float_as_uint(f);
  u += 0x7fffu + ((u >> 16) & 1u);   // RNE
  return (unsigned short)(u >> 16);
}
__device__ __forceinline__ float bf2f(unsigned short h){
  return __uint_as_float(((unsigned)h) << 16);
}
__device__ __forceinline__ f32x4 mfma16(bf16x8 a, bf16x8 b, f32x4 c){
  return __builtin_amdgcn_mfma_f32_16x16x32_bf16(a, b, c, 0, 0, 0);
}
__device__ __forceinline__ f32x16 mfma32(bf16x8 a, bf16x8 b, f32x16 c){
  return __builtin_amdgcn_mfma_f32_32x32x16_bf16(a, b, c, 0, 0, 0);
}
__device__ __forceinline__ void gld_lds16(const unsigned short* g, unsigned short* l){
  __builtin_amdgcn_global_load_lds(
      (const __attribute__((address_space(1))) unsigned int*)(const void*)g,
      (__attribute__((address_space(3))) unsigned int*)(void*)l, 16, 0, 0);
}
__device__ __forceinline__ bf16x8 pack8(float4 a, float4 b){
  ushort8_t u = { f2bf(a.x), f2bf(a.y), f2bf(a.z), f2bf(a.w),
                  f2bf(b.x), f2bf(b.y), f2bf(b.z), f2bf(b.w) };
  return *(bf16x8*)&u;
}

// ---------------- scalars: STG regularizers + zero accumulators ------------
__global__ void k_scalars(const float* __restrict__ mux, const float* __restrict__ muy,
                          float* __restrict__ sx, float* __restrict__ sy,
                          float* __restrict__ scal){
  __shared__ float red[512];
  int v = blockIdx.x;
  const float* mu = v ? muy : mux;
  int t = threadIdx.x;
  float a = 0.5f * (1.f + erff(mu[t]       * 1.41421356237f));
  float b = 0.5f * (1.f + erff(mu[t + 512] * 1.41421356237f));
  red[t] = a + b;
  __syncthreads();
  for (int s = 256; s > 0; s >>= 1){
    if (t < s) red[t] += red[t + s];
    __syncthreads();
  }
  if (t == 0) scal[2 + v] = 0.1f * red[0] / 1024.f;
  if (v == 0 && t < 3) scal[4 + t] = 0.f;   // trace acc + two uint norm slots
  if (t < 256) (v ? sy : sx)[t] = 0.f;
}

// ---------------- build W'^T = (diag(gate)*W)^T in bf16, [256][1024] -------
__global__ void k_prep(const float* __restrict__ Wx, const float* __restrict__ Wy,
                       const float* __restrict__ mux, const float* __restrict__ muy,
                       unsigned short* __restrict__ WTx, unsigned short* __restrict__ WTy){
  int v = blockIdx.y;
  const float* W  = v ? Wy  : Wx;
  const float* mu = v ? muy : mux;
  unsigned short* WT = v ? WTy : WTx;
  int j = threadIdx.x;
  #pragma unroll
  for (int r = 0; r < 4; ++r){
    int k = blockIdx.x * 4 + r;
    float g = fminf(fmaxf(mu[k] + 0.5f, 0.f), 1.f);
    WT[(size_t)j * DXF + k] = f2bf(g * W[(size_t)k * DD + j]);
  }
}

// ---------------- big GEMM: Xh = X @ W'  (65536x1024 @ 1024x256) -> bf16 ---
// block: 256 thr (4 waves), 128 rows; wave tile 32x256; 32x32x16 MFMA
// A: global->reg->cvt (HBM stream, no LDS). B: global_load_lds dbuf (L2).
__global__ __launch_bounds__(256, 2) void k_gemm2(
    const float* __restrict__ X, const float* __restrict__ Y,
    const unsigned short* __restrict__ WTx, const unsigned short* __restrict__ WTy,
    unsigned short* __restrict__ Xhb, unsigned short* __restrict__ Yhb){
  const float* A = blockIdx.z ? Y : X;
  const unsigned short* WT = blockIdx.z ? WTy : WTx;
  unsigned short* Out = blockIdx.z ? Yhb : Xhb;

  // staging: [buf2][ks2][kh2][col256][8] shorts = 2 x 8192 shorts (32KB)
  // writeout reuses all 32768 shorts (64KB)
  __shared__ unsigned short lds[32768];

  int tid = threadIdx.x, lane = tid & 63, wid = tid >> 6;
  int row0 = blockIdx.x * 128;
  int arow = row0 + wid * 32 + (lane & 31);
  const float* ap = A + (size_t)arow * DXF + ((lane >> 5) << 3);

  f32x16 acc[8] = {};

  auto stage = [&](int buf, int k0){
    #pragma unroll
    for (int r = 0; r < 4; ++r){
      const unsigned short* s = WT + (size_t)tid * DXF + k0 + (r >> 1) * 16 + (r & 1) * 8;
      unsigned short* l = lds + buf * 8192 + r * 2048 + tid * 8;
      gld_lds16(s, l);
    }
  };

  stage(0, 0);
  for (int ks = 0; ks < 32; ++ks){
    int k0 = ks * 32;
    __syncthreads();
    if (ks + 1 < 32) stage((ks + 1) & 1, k0 + 32);

    float4 a0 = *(const float4*)(ap + k0);
    float4 a1 = *(const float4*)(ap + k0 + 4);
    float4 a2 = *(const float4*)(ap + k0 + 16);
    float4 a3 = *(const float4*)(ap + k0 + 20);
    bf16x8 af0 = pack8(a0, a1);
    bf16x8 af1 = pack8(a2, a3);

    const unsigned short* bb = lds + (ks & 1) * 8192 + ((lane >> 5) << 11) + ((lane & 31) << 3);
    #pragma unroll
    for (int ni = 0; ni < 8; ++ni){
      bf16x8 b0 = *(const bf16x8*)(bb + ni * 256);
      acc[ni] = mfma32(af0, b0, acc[ni]);
    }
    #pragma unroll
    for (int ni = 0; ni < 8; ++ni){
      bf16x8 b1 = *(const bf16x8*)(bb + 4096 + ni * 256);
      acc[ni] = mfma32(af1, b1, acc[ni]);
    }
  }

  // epilogue: LDS transpose for coalesced bf16 stores
  __syncthreads();
  unsigned short* wl = lds + wid * 8192;   // 32 rows x 256 cols per wave
  #pragma unroll
  for (int ni = 0; ni < 8; ++ni){
    int col = ni * 32 + (lane & 31);
    #pragma unroll
    for (int reg = 0; reg < 16; ++reg){
      int row = (reg & 3) + 8 * (reg >> 2) + 4 * (lane >> 5);
      wl[row * 256 + col] = f2bf(acc[ni][reg]);
    }
  }
  __syncthreads();
  unsigned short* ob = Out + (size_t)row0 * DD;
  #pragma unroll
  for (int r = 0; r < 16; ++r){
    int off = (r * 256 + tid) * 8;
    *(ushort8_t*)(ob + off) = *(const ushort8_t*)(lds + off);
  }
}

// ---------------- Gram kernel: split-K partials of Xh^T Xh / Yh^T Yh / Yh^T Xh
__global__ __launch_bounds__(512) void k_gram(
    const unsigned short* __restrict__ Xhb, const unsigned short* __restrict__ Yhb,
    float* __restrict__ part, float* __restrict__ sx, float* __restrict__ sy, int P){
  int type = blockIdx.z;                   // 0:xx 1:yy 2:yx
  int p = blockIdx.x;
  int chunk = N_S / P;
  int r0 = p * chunk;
  const unsigned short* Asrc = (type == 0) ? Xhb : Yhb;
  const unsigned short* Bsrc = (type == 1) ? Yhb : Xhb;
  bool dualB = (type == 2);

  __shared__ unsigned short At[256][40];
  __shared__ unsigned short Bt[256][40];

  int tid = threadIdx.x;
  int lane = tid & 63, wid = tid >> 6;
  int wr = wid >> 1, wc = wid & 1;

  f32x4 acc[4][8] = {};
  float cs0 = 0.f, cs1 = 0.f;

  int cp  = tid & 127;
  int kb0 = tid >> 7;

  unsigned ua[2][4], ub[2][4];

  auto loadT = [&](int ks){
    int base = r0 + ks * 32;
    #pragma unroll
    for (int r = 0; r < 2; ++r){
      int kb = kb0 + r * 4;
      #pragma unroll
      for (int kr = 0; kr < 4; ++kr){
        ua[r][kr] = *(const unsigned*)(Asrc + (size_t)(base + kb * 4 + kr) * DD + cp * 2);
        if (dualB)
          ub[r][kr] = *(const unsigned*)(Bsrc + (size_t)(base + kb * 4 + kr) * DD + cp * 2);
      }
    }
  };
  auto storeT = [&](){
    #pragma unroll
    for (int r = 0; r < 2; ++r){
      int kb = kb0 + r * 4;
      ushort4_t lo = { (unsigned short)ua[r][0], (unsigned short)ua[r][1],
                       (unsigned short)ua[r][2], (unsigned short)ua[r][3] };
      ushort4_t hi = { (unsigned short)(ua[r][0] >> 16), (unsigned short)(ua[r][1] >> 16),
                       (unsigned short)(ua[r][2] >> 16), (unsigned short)(ua[r][3] >> 16) };
      *(ushort4_t*)&At[cp * 2][kb * 4]     = lo;
      *(ushort4_t*)&At[cp * 2 + 1][kb * 4] = hi;
      if (type < 2){
        #pragma unroll
        for (int kr = 0; kr < 4; ++kr){
          cs0 += bf2f((unsigned short)ua[r][kr]);
          cs1 += bf2f((unsigned short)(ua[r][kr] >> 16));
        }
      }
      if (dualB){
        ushort4_t lob = { (unsigned short)ub[r][0], (unsigned short)ub[r][1],
                          (unsigned short)ub[r][2], (unsigned short)ub[r][3] };
        ushort4_t hib = { (unsigned short)(ub[r][0] >> 16), (unsigned short)(ub[r][1] >> 16),
                          (unsigned short)(ub[r][2] >> 16), (unsigned short)(ub[r][3] >> 16) };
        *(ushort4_t*)&Bt[cp * 2][kb * 4]     = lob;
        *(ushort4_t*)&Bt[cp * 2 + 1][kb * 4] = hib;
      }
    }
  };

  unsigned short (*Btp)[40] = dualB ? Bt : At;

  int KS = chunk / 32;
  loadT(0);
  for (int ks = 0; ks < KS; ++ks){
    __syncthreads();
    storeT();
    __syncthreads();
    if (ks + 1 < KS) loadT(ks + 1);
    bf16x8 af[4], bfv[8];
    #pragma unroll
    for (int mi = 0; mi < 4; ++mi)
      af[mi] = *(const bf16x8*)&At[wr * 64 + mi * 16 + (lane & 15)][(lane >> 4) * 8];
    #pragma unroll
    for (int ni = 0; ni < 8; ++ni)
      bfv[ni] = *(const bf16x8*)&Btp[wc * 128 + ni * 16 + (lane & 15)][(lane >> 4) * 8];
    #pragma unroll
    for (int mi = 0; mi < 4; ++mi)
      #pragma unroll
      for (int ni = 0; ni < 8; ++ni)
        acc[mi][ni] = mfma16(af[mi], bfv[ni], acc[mi][ni]);
  }

  float* dst = part + ((size_t)p * 3 + type) * 65536;
  #pragma unroll
  for (int mi = 0; mi < 4; ++mi)
    #pragma unroll
    for (int ni = 0; ni < 8; ++ni)
      #pragma unroll
      for (int rr = 0; rr < 4; ++rr){
        int grow = wr * 64 + mi * 16 + (lane >> 4) * 4 + rr;
        int gcol = wc * 128 + ni * 16 + (lane & 15);
        dst[(size_t)grow * 256 + gcol] = acc[mi][ni][rr];
      }

  if (type < 2){
    __syncthreads();
    float* red = (float*)&At[0][0];
    red[kb0 * 256 + cp * 2]     = cs0;
    red[kb0 * 256 + cp * 2 + 1] = cs1;
    __syncthreads();
    if (tid < 256){
      float s = red[tid] + red[256 + tid] + red[512 + tid] + red[768 + tid];
      atomicAdd((type == 0 ? sx : sy) + tid, s);
    }
  }
}

// ---------------- reduce partials -> A, B (fp32 + bf16), Cyx bf16 (+T) -----
__global__ void k_reduce(const float* __restrict__ part, const float* __restrict__ sx,
                         const float* __restrict__ sy, float* __restrict__ Am,
                         float* __restrict__ Bm,
                         unsigned short* __restrict__ Abf, unsigned short* __restrict__ Bbf,
                         unsigned short* __restrict__ Cbf, unsigned short* __restrict__ CbfT,
                         int P){
  int i = blockIdx.x, j = threadIdx.x;
  size_t idx = (size_t)i * 256 + j;
  float gxx = 0.f, gyy = 0.f, gyx = 0.f;
  for (int p = 0; p < P; ++p){
    const float* b = part + (size_t)p * 3 * 65536;
    gxx += b[idx];
    gyy += b[65536 + idx];
    gyx += b[131072 + idx];
  }
  float invn1 = 1.f / NM1;
  float invn  = 1.f / (float)N_S;
  float sxi = sx[i], sxj = sx[j], syi = sy[i], syj = sy[j];
  float diag = (i == j) ? 1.f : 0.f;
  float am = (gyy - syi * syj * invn) * invn1 + diag * (2.f * EPSR);
  float bm = (gxx - sxi * sxj * invn) * invn1 + diag * EPSR;
  float cv = (gyx - syi * sxj * invn) * invn1;
  Am[idx] = am;  Bm[idx] = bm;
  Abf[idx] = f2bf(am);
  Bbf[idx] = f2bf(bm);
  Cbf[idx] = f2bf(cv);
  CbfT[(size_t)j * 256 + i] = f2bf(cv);
}

// ---------------- cooperative tail: norms, init, 8x NS, U/V, trace ---------
__device__ __forceinline__ f32x4 ns_tile(const unsigned short* __restrict__ Ar,
                                         const unsigned short* __restrict__ Br,
                                         int rt, int ct, int lane){
  const unsigned short* ap = Ar + (size_t)(rt * 16 + (lane & 15)) * 256 + ((lane >> 4) << 3);
  const unsigned short* bp = Br + (size_t)(ct * 16 + (lane & 15)) * 256 + ((lane >> 4) << 3);
  f32x4 acc = {};
  #pragma unroll
  for (int kb = 0; kb < 8; ++kb){
    bf16x8 a = *(const bf16x8*)(ap + kb * 32);
    bf16x8 b = *(const bf16x8*)(bp + kb * 32);
    acc = mfma16(a, b, acc);
  }
  return acc;
}

__global__ __launch_bounds__(512) void k_ns(
    const float* __restrict__ Am, const float* __restrict__ Bm,
    const unsigned short* __restrict__ Abf, const unsigned short* __restrict__ Bbf,
    const unsigned short* __restrict__ Cbf, const unsigned short* __restrict__ CbfT,
    unsigned short* __restrict__ X0, unsigned short* __restrict__ X1,
    unsigned short* __restrict__ Tb, float* __restrict__ U, float* __restrict__ V,
    float* __restrict__ scal, float* __restrict__ out){
  cg::grid_group grid = cg::this_grid();
  __shared__ float red[512];
  int bid = blockIdx.x, tid = threadIdx.x;
  int lane = tid & 63;
  unsigned* su = (unsigned*)scal;

  // phase 0: inf-norms of A (blocks 0-15) and B (blocks 16-31)
  {
    int mat = bid >> 4;
    int row = (bid & 15) * 16 + (tid >> 5);
    const float* M = mat ? Bm : Am;
    float s = 0.f;
    for (int j = tid & 31; j < 256; j += 32) s += fabsf(M[(size_t)row * 256 + j]);
    #pragma unroll
    for (int o = 16; o > 0; o >>= 1) s += __shfl_xor(s, o);
    if ((lane & 31) == 0) atomicMax(su + 5 + mat, __float_as_uint(s));
  }
  grid.sync();

  // phase 1: X0 = alpha * I (bf16), both matrices
  float aa = 1.f / __uint_as_float(su[5]);
  float ab = 1.f / __uint_as_float(su[6]);
  #pragma unroll
  for (int r = 0; r < 8; ++r){
    int idx = (bid * 512 + tid) + r * 16384;
    int mat = idx >> 16, e = idx & 65535;
    X0[idx] = ((e >> 8) == (e & 255)) ? f2bf(mat ? ab : aa) : (unsigned short)0;
  }
  grid.sync();

  int wave = bid * 8 + (tid >> 6);          // 0..255 ; 512 tiles total
  unsigned short *Xc = X0, *Xn = X1;

  for (int it = 0; it < 8; ++it){
    // half 1: T = M @ X
    #pragma unroll
    for (int s = 0; s < 2; ++s){
      int t = wave * 2 + s;
      int mat = t >> 8, rt = (t >> 4) & 15, ct = t & 15;
      const unsigned short* M = mat ? Bbf : Abf;
      f32x4 acc = ns_tile(M, Xc + mat * 65536, rt, ct, lane);
      int col = ct * 16 + (lane & 15);
      #pragma unroll
      for (int rr = 0; rr < 4; ++rr){
        int row = rt * 16 + (lane >> 4) * 4 + rr;
        Tb[mat * 65536 + row * 256 + col] = f2bf(acc[rr]);
      }
    }
    grid.sync();
    // half 2: X' = 2X - X @ T
    #pragma unroll
    for (int s = 0; s < 2; ++s){
      int t = wave * 2 + s;
      int mat = t >> 8, rt = (t >> 4) & 15, ct = t & 15;
      f32x4 acc = ns_tile(Xc + mat * 65536, Tb + mat * 65536, rt, ct, lane);
      int col = ct * 16 + (lane & 15);
      #pragma unroll
      for (int rr = 0; rr < 4; ++rr){
        int row = rt * 16 + (lane >> 4) * 4 + rr;
        size_t o = (size_t)mat * 65536 + row * 256 + col;
        Xn[o] = f2bf(2.f * bf2f(Xc[o]) - acc[rr]);
      }
    }
    grid.sync();
    unsigned short* tmp = Xc; Xc = Xn; Xn = tmp;
  }

  // U = XA @ Cyx (B-op = CbfT), V = XB @ Cyx^T (B-op = Cbf); fp32 out
  #pragma unroll
  for (int s = 0; s < 2; ++s){
    int t = wave * 2 + s;
    int mat = t >> 8, rt = (t >> 4) & 15, ct = t & 15;
    f32x4 acc = ns_tile(Xc + mat * 65536, mat ? Cbf : CbfT, rt, ct, lane);
    float* D = mat ? V : U;
    int col = ct * 16 + (lane & 15);
    #pragma unroll
    for (int rr = 0; rr < 4; ++rr){
      int row = rt * 16 + (lane >> 4) * 4 + rr;
      D[row * 256 + col] = acc[rr];
    }
  }
  grid.sync();

  // trace(U @ V)
  float tr = 0.f;
  #pragma unroll
  for (int r = 0; r < 4; ++r){
    int idx = bid * 2048 + r * 512 + tid;
    int i = idx >> 8, j = idx & 255;
    tr += U[idx] * V[j * 256 + i];
  }
  red[tid] = tr;
  __syncthreads();
  for (int s = 256; s > 0; s >>= 1){
    if (tid < s) red[tid] += red[tid + s];
    __syncthreads();
  }
  if (tid == 0) atomicAdd(scal + 4, red[0]);
  grid.sync();
  if (bid == 0 && tid == 0)
    out[0] = -scal[4] / 256.f + scal[2] + scal[3];
}

extern "C" void kernel_launch(void* const* d_in, const int* in_sizes, int n_in,
                              void* d_out, int out_size, void* d_ws, size_t ws_size,
                              hipStream_t stream){
  (void)in_sizes; (void)n_in; (void)out_size;
  const float* X   = (const float*)d_in[0];
  const float* Y   = (const float*)d_in[1];
  const float* mux = (const float*)d_in[2];
  const float* muy = (const float*)d_in[3];
  const float* Wx  = (const float*)d_in[4];
  const float* Wy  = (const float*)d_in[6];
  float* out = (float*)d_out;
  char* ws = (char*)d_ws;

  const size_t MB = 1ull << 20;
  const size_t KB = 1024;
  size_t oXHB = 0;
  size_t oYHB = 32 * MB;
  size_t oWTX = 64 * MB;
  size_t oWTY = oWTX + 512 * KB;
  size_t oSX  = oWTY + 512 * KB;
  size_t oSY  = oSX + 4 * KB;
  size_t oSC  = oSY + 4 * KB;
  size_t oA   = oSC + 4 * KB;
  size_t oB   = oA   + 256 * KB;
  size_t oABF = oB   + 256 * KB;
  size_t oBBF = oABF + 128 * KB;
  size_t oCBF = oBBF + 128 * KB;
  size_t oCBT = oCBF + 128 * KB;
  size_t oX0  = oCBT + 128 * KB;
  size_t oX1  = oX0  + 256 * KB;
  size_t oTB  = oX1  + 256 * KB;
  size_t oU   = oTB  + 256 * KB;
  size_t oV   = oU   + 256 * KB;
  size_t oPart = 68 * MB;

  size_t per = 3ull * 65536 * 4;
  int P = 64;
  while (P > 1 && oPart + (size_t)P * per > ws_size) P >>= 1;

  unsigned short* Xhb = (unsigned short*)(ws + oXHB);
  unsigned short* Yhb = (unsigned short*)(ws + oYHB);
  unsigned short* WTx = (unsigned short*)(ws + oWTX);
  unsigned short* WTy = (unsigned short*)(ws + oWTY);
  float* sx   = (float*)(ws + oSX);
  float* sy   = (float*)(ws + oSY);
  float* scal = (float*)(ws + oSC);
  float* Am   = (float*)(ws + oA);
  float* Bm   = (float*)(ws + oB);
  unsigned short* Abf  = (unsigned short*)(ws + oABF);
  unsigned short* Bbf  = (unsigned short*)(ws + oBBF);
  unsigned short* Cbf  = (unsigned short*)(ws + oCBF);
  unsigned short* CbfT = (unsigned short*)(ws + oCBT);
  unsigned short* X0   = (unsigned short*)(ws + oX0);
  unsigned short* X1   = (unsigned short*)(ws + oX1);
  unsigned short* Tb   = (unsigned short*)(ws + oTB);
  float* U    = (float*)(ws + oU);
  float* V    = (float*)(ws + oV);
  float* part = (float*)(ws + oPart);

  k_scalars<<<2, 512, 0, stream>>>(mux, muy, sx, sy, scal);
  k_prep<<<dim3(256, 2), 256, 0, stream>>>(Wx, Wy, mux, muy, WTx, WTy);
  k_gemm2<<<dim3(512, 1, 2), 256, 0, stream>>>(X, Y, WTx, WTy, Xhb, Yhb);
  k_gram<<<dim3(P, 1, 3), 512, 0, stream>>>(Xhb, Yhb, part, sx, sy, P);
  k_reduce<<<256, 256, 0, stream>>>(part, sx, sy, Am, Bm, Abf, Bbf, Cbf, CbfT, P);

  void* args[] = { (void*)&Am, (void*)&Bm, (void*)&Abf, (void*)&Bbf,
                   (void*)&Cbf, (void*)&CbfT, (void*)&X0, (void*)&X1,
                   (void*)&Tb, (void*)&U, (void*)&V, (void*)&scal, (void*)&out };
  hipLaunchCooperativeKernel((const void*)k_ns, dim3(32), dim3(512), args, 0, stream);
}